// Round 8
// baseline (661.488 us; speedup 1.0000x reference)
//
#include <hip/hip_runtime.h>
#include <hip/hip_bf16.h>

constexpr int BATCH = 4;
constexpr int MEMK  = 128;
constexpr int CDIM  = 768;
constexpr int NH    = 12;
constexpr int HD    = 64;
constexpr int LDIM  = 2177;              // MEMK + 1 + 2048
constexpr int MROWS = BATCH * LDIM;      // 8708
constexpr int LPAD  = 2240;              // Vt row length

typedef __attribute__((ext_vector_type(4))) float f32x4;
typedef __attribute__((ext_vector_type(8))) short short8;
typedef __attribute__((ext_vector_type(4))) short s16x4;

__device__ __forceinline__ short f2bf(float f) {
    unsigned u = __builtin_bit_cast(unsigned, f);
    u = (u + 0x7FFFu + ((u >> 16) & 1u)) >> 16;
    return (short)u;
}
__device__ __forceinline__ float bf2f(short s) {
    unsigned u = ((unsigned)(unsigned short)s) << 16;
    return __builtin_bit_cast(float, u);
}
__device__ __forceinline__ void split2(float v, short& h, short& l) {
    h = f2bf(v);
    l = f2bf(v - bf2f(h));
}
__device__ __forceinline__ void gload16(const void* g, void* l) {
    __builtin_amdgcn_global_load_lds(
        (const __attribute__((address_space(1))) void*)g,
        (__attribute__((address_space(3))) void*)l, 16, 0, 0);
}

// ---------------- convert fp32 -> bf16 hi/lo planes (row-major) ----------------
__global__ __launch_bounds__(256)
void convsplit_kernel(const float* __restrict__ src, short* __restrict__ h,
                      short* __restrict__ l, int n4)
{
    for (int i = blockIdx.x * blockDim.x + threadIdx.x; i < n4;
         i += gridDim.x * blockDim.x) {
        float4 v = ((const float4*)src)[i];
        short hs[4], ls[4];
        split2(v.x, hs[0], ls[0]); split2(v.y, hs[1], ls[1]);
        split2(v.z, hs[2], ls[2]); split2(v.w, hs[3], ls[3]);
        ((short4*)h)[i] = make_short4(hs[0], hs[1], hs[2], hs[3]);
        ((short4*)l)[i] = make_short4(ls[0], ls[1], ls[2], ls[3]);
    }
}

// ---------------- transpose + convert: W[K][N] -> Wt hi/lo [N][K] ----------------
__global__ __launch_bounds__(256)
void transconv_kernel(const float* __restrict__ W, short* __restrict__ th,
                      short* __restrict__ tl, int K, int N)
{
    __shared__ float tile[32][33];
    const int k0 = blockIdx.y * 32, n0 = blockIdx.x * 32;
    const int tx = threadIdx.x & 31, ty = threadIdx.x >> 5;   // 32 x 8
#pragma unroll
    for (int j = 0; j < 4; ++j)
        tile[ty + j * 8][tx] = W[(size_t)(k0 + ty + j * 8) * N + n0 + tx];
    __syncthreads();
#pragma unroll
    for (int j = 0; j < 4; ++j) {
        float v = tile[tx][ty + j * 8];
        short hi, lo; split2(v, hi, lo);
        size_t o = (size_t)(n0 + ty + j * 8) * K + k0 + tx;
        th[o] = hi; tl[o] = lo;
    }
}

// ---------------- MFMA GEMM: A[M][768] (hi/lo) x Bt[N][768] (hi/lo) ----------------
// EPI: 0 = QKV scatter epilogue (Q pre-scaled by 0.125), 1 = plain fp32 out.
template<int EPI>
__global__ __launch_bounds__(256)
void gemm_mfma_kernel(const short* __restrict__ Ah, const short* __restrict__ Al,
                      const short* __restrict__ Bh, const short* __restrict__ Bl,
                      short* __restrict__ Qh, short* __restrict__ Ql,
                      short* __restrict__ Kh, short* __restrict__ Kl,
                      short* __restrict__ Vth, short* __restrict__ Vtl,
                      float* __restrict__ Of)
{
    constexpr int KD = 768;
    __shared__ short lds[4][128 * 32];   // Ah, Al, Bh, Bl tiles (8KB each)
    const int tid  = threadIdx.x;
    const int lane = tid & 63;
    const int w    = tid >> 6;
    const int wr = w >> 1, wc = w & 1;
    const int lr = lane & 15, lg = lane >> 4;
    const int row0 = blockIdx.y * 128, col0 = blockIdx.x * 128;

    f32x4 acc[4][4];
#pragma unroll
    for (int m = 0; m < 4; ++m)
#pragma unroll
        for (int n = 0; n < 4; ++n) acc[m][n] = (f32x4){0.f, 0.f, 0.f, 0.f};

    for (int kt = 0; kt < KD / 32; ++kt) {
        const int k0 = kt * 32;
        __syncthreads();
#pragma unroll
        for (int q = 0; q < 2; ++q) {
            const int c = q * 256 + tid;
            const int r = c >> 2, s = c & 3;
            const int ar = min(row0 + r, MROWS - 1);
            const int br = col0 + r;
            const size_t aoff = (size_t)ar * KD + k0 + s * 8;
            const size_t boff = (size_t)br * KD + k0 + s * 8;
            gload16(Ah + aoff, &lds[0][c * 8]);
            gload16(Al + aoff, &lds[1][c * 8]);
            gload16(Bh + boff, &lds[2][c * 8]);
            gload16(Bl + boff, &lds[3][c * 8]);
        }
        __syncthreads();

        short8 afh[4], afl[4], bfh[4], bfl[4];
#pragma unroll
        for (int m = 0; m < 4; ++m) {
            int r = wr * 64 + m * 16 + lr;
            afh[m] = *(const short8*)&lds[0][r * 32 + lg * 8];
            afl[m] = *(const short8*)&lds[1][r * 32 + lg * 8];
        }
#pragma unroll
        for (int n = 0; n < 4; ++n) {
            int r = wc * 64 + n * 16 + lr;
            bfh[n] = *(const short8*)&lds[2][r * 32 + lg * 8];
            bfl[n] = *(const short8*)&lds[3][r * 32 + lg * 8];
        }
#pragma unroll
        for (int m = 0; m < 4; ++m)
#pragma unroll
            for (int n = 0; n < 4; ++n) {
                f32x4 a = acc[m][n];
                a = __builtin_amdgcn_mfma_f32_16x16x32_bf16(afh[m], bfh[n], a, 0, 0, 0);
                a = __builtin_amdgcn_mfma_f32_16x16x32_bf16(afl[m], bfh[n], a, 0, 0, 0);
                a = __builtin_amdgcn_mfma_f32_16x16x32_bf16(afh[m], bfl[n], a, 0, 0, 0);
                acc[m][n] = a;
            }
    }

#pragma unroll
    for (int n = 0; n < 4; ++n) {
        const int colb = col0 + wc * 64 + n * 16;
        if (EPI == 0) {
            const int sel = colb / CDIM;
            const int c0  = colb - sel * CDIM;
            const int h   = c0 >> 6;
            const int dd  = (c0 & 63) + lr;
            const float scl = (sel == 0) ? 0.125f : 1.0f;   // exact: Q pre-scale
#pragma unroll
            for (int m = 0; m < 4; ++m)
#pragma unroll
                for (int e = 0; e < 4; ++e) {
                    int mg = row0 + wr * 64 + m * 16 + lg * 4 + e;
                    if (mg >= MROWS) continue;
                    int b = mg / LDIM, l = mg - b * LDIM;
                    short hi, lo; split2(acc[m][n][e] * scl, hi, lo);
                    if (sel == 0) {
                        size_t o = (((size_t)(b * NH + h)) * LDIM + l) * HD + dd;
                        Qh[o] = hi; Ql[o] = lo;
                    } else if (sel == 1) {
                        size_t o = (((size_t)(b * NH + h)) * LDIM + l) * HD + dd;
                        Kh[o] = hi; Kl[o] = lo;
                    } else {
                        size_t o = (((size_t)(b * NH + h)) * HD + dd) * LPAD + l;
                        Vth[o] = hi; Vtl[o] = lo;
                    }
                }
        } else {
#pragma unroll
            for (int m = 0; m < 4; ++m)
#pragma unroll
                for (int e = 0; e < 4; ++e) {
                    int mg = row0 + wr * 64 + m * 16 + lg * 4 + e;
                    if (mg >= MROWS) continue;
                    Of[(size_t)mg * CDIM + colb + lr] = acc[m][n][e];
                }
        }
    }
}

// ---------------- MFMA flash attention v3 ----------------
// Swapped QK^T; P stays in registers (k-slot remapped PV: sigma_m(lg,j) =
// (2m + (j>=4))*16 + lg*4 + (j&3) -- A/B consistent, no redistribution).
// LDS = K+V only (32KB) -> 4 blocks/CU.
__global__ __launch_bounds__(256, 4)
void attn_mfma_kernel(const short* __restrict__ Qh, const short* __restrict__ Ql,
                      const short* __restrict__ Kh, const short* __restrict__ Kl,
                      const short* __restrict__ Vth, const short* __restrict__ Vtl,
                      short* __restrict__ Yh, short* __restrict__ Yl)
{
    __shared__ short Klds[2][64 * 64];   // [plane][key][d] XOR-swizzled, 16KB
    __shared__ short Vlds[2][64 * 64];   // [plane][d][key] XOR-swizzled, 16KB
    const int tid  = threadIdx.x;
    const int lane = tid & 63;
    const int w    = tid >> 6;
    const int lr = lane & 15, lg = lane >> 4;
    const int bh = blockIdx.y;
    const int b = bh / NH, h = bh % NH;
    constexpr int NXB = (LDIM + 127) / 128;          // 18
    const int qb = (NXB - 1 - (int)blockIdx.x) * 128; // heavy blocks first
    const int qw = qb + w * 32;

    int mynt;
    if (qw >= LDIM) mynt = 0;
    else if (qw <= MEMK && MEMK <= qw + 31) mynt = (LDIM - 1) / 64 + 1;
    else if (qw + 31 < MEMK) mynt = MEMK / 64 + 1;
    else mynt = min(qw + 31, LDIM - 1) / 64 + 1;
    int bnt;
    if (qb <= MEMK && MEMK <= qb + 127) bnt = (LDIM - 1) / 64 + 1;
    else if (qb + 127 < MEMK) bnt = MEMK / 64 + 1;
    else bnt = min(qb + 127, LDIM - 1) / 64 + 1;

    int rkmax[2];
#pragma unroll
    for (int rg = 0; rg < 2; ++rg) {
        int q = qw + rg * 16 + lr;
        rkmax[rg] = (q < MEMK) ? MEMK : (q == MEMK) ? (LDIM - 1)
                  : (q < LDIM) ? q : -1;
    }

    // Q fragments (B-operand), pre-scaled by 0.125 at QKV epilogue
    short8 qfh[2][2], qfl[2][2];
#pragma unroll
    for (int rg = 0; rg < 2; ++rg)
#pragma unroll
        for (int dc = 0; dc < 2; ++dc) {
            int qr = min(qw + rg * 16 + lr, LDIM - 1);
            size_t off = ((size_t)bh * LDIM + qr) * HD + dc * 32 + lg * 8;
            qfh[rg][dc] = *(const short8*)(Qh + off);
            qfl[rg][dc] = *(const short8*)(Ql + off);
        }

    f32x4 O[2][4];
#pragma unroll
    for (int rg = 0; rg < 2; ++rg)
#pragma unroll
        for (int g = 0; g < 4; ++g) O[rg][g] = (f32x4){0.f, 0.f, 0.f, 0.f};
    float mrun[2] = {-INFINITY, -INFINITY};
    float lsum[2] = {0.f, 0.f};

    const short* Khb = Kh  + (size_t)bh * LDIM * HD;
    const short* Klb = Kl  + (size_t)bh * LDIM * HD;
    const short* Vhb = Vth + (size_t)bh * HD * LPAD;
    const short* Vlb = Vtl + (size_t)bh * HD * LPAD;

    for (int t = 0; t < bnt; ++t) {
        const int k0 = t * 64;
        __syncthreads();                 // prev-tile LDS reads complete
#pragma unroll
        for (int it = 0; it < 2; ++it) {
            int c = it * 256 + tid;      // 16B chunk id, lane-stride 16B
            int row = c >> 3, j = c & 7;
            int sw = ((j ^ (row & 7)) << 3);
            int krow = min(k0 + row, LDIM - 1);
            gload16(Khb + (size_t)krow * HD + sw, &Klds[0][c * 8]);
            gload16(Klb + (size_t)krow * HD + sw, &Klds[1][c * 8]);
            gload16(Vhb + (size_t)row * LPAD + k0 + sw, &Vlds[0][c * 8]);
            gload16(Vlb + (size_t)row * LPAD + k0 + sw, &Vlds[1][c * 8]);
        }
        __syncthreads();                 // vmcnt drained by compiler

        if (t < mynt) {
            // ---- QK^T swapped: S[key][q], A=K from LDS, B=Q regs ----
            f32x4 S[2][4];
#pragma unroll
            for (int kg = 0; kg < 4; ++kg) {
                short8 kfh[2], kfl[2];
#pragma unroll
                for (int dc = 0; dc < 2; ++dc) {
                    int key = kg * 16 + lr;
                    int cj = (dc * 4 + lg) ^ (key & 7);
                    kfh[dc] = *(const short8*)&Klds[0][key * 64 + cj * 8];
                    kfl[dc] = *(const short8*)&Klds[1][key * 64 + cj * 8];
                }
#pragma unroll
                for (int rg = 0; rg < 2; ++rg) {
                    f32x4 a = (f32x4){0.f, 0.f, 0.f, 0.f};
#pragma unroll
                    for (int dc = 0; dc < 2; ++dc) {
                        a = __builtin_amdgcn_mfma_f32_16x16x32_bf16(kfh[dc], qfh[rg][dc], a, 0, 0, 0);
                        a = __builtin_amdgcn_mfma_f32_16x16x32_bf16(kfl[dc], qfh[rg][dc], a, 0, 0, 0);
                        a = __builtin_amdgcn_mfma_f32_16x16x32_bf16(kfh[dc], qfl[rg][dc], a, 0, 0, 0);
                    }
                    S[rg][kg] = a;
                }
            }
            // ---- softmax (rows lane-local), P -> registers as bf16 hi/lo ----
            float corr2[2];
            s16x4 pah[2][4], pal[2][4];
#pragma unroll
            for (int rg = 0; rg < 2; ++rg) {
                const int rel = rkmax[rg] - k0 - lg * 4;
                float mx = -INFINITY;
#pragma unroll
                for (int kg = 0; kg < 4; ++kg)
#pragma unroll
                    for (int e = 0; e < 4; ++e) {
                        float v = S[rg][kg][e];
                        v = (kg * 16 + e <= rel) ? v : -INFINITY;
                        S[rg][kg][e] = v;
                        mx = fmaxf(mx, v);
                    }
                mx = fmaxf(mx, __shfl_xor(mx, 16));
                mx = fmaxf(mx, __shfl_xor(mx, 32));
                float nm = fmaxf(mrun[rg], mx);
                float corr = (nm == -INFINITY) ? 1.f : __expf(mrun[rg] - nm);
                mrun[rg] = nm;
                float ps = 0.f;
#pragma unroll
                for (int kg = 0; kg < 4; ++kg)
#pragma unroll
                    for (int e = 0; e < 4; ++e) {
                        float v = S[rg][kg][e];
                        float pp = (v == -INFINITY) ? 0.f : __expf(v - nm);
                        ps += pp;
                        short hh, ll; split2(pp, hh, ll);
                        pah[rg][kg][e] = hh; pal[rg][kg][e] = ll;
                    }
                ps += __shfl_xor(ps, 16);
                ps += __shfl_xor(ps, 32);
                lsum[rg] = lsum[rg] * corr + ps;
                corr2[rg] = corr;
            }
            // ---- rescale O (corr redistributed q=lr -> q=lg*4+e) ----
#pragma unroll
            for (int rg = 0; rg < 2; ++rg)
#pragma unroll
                for (int e = 0; e < 4; ++e) {
                    float cc = __shfl(corr2[rg], lg * 4 + e);
#pragma unroll
                    for (int ddg = 0; ddg < 4; ++ddg) O[rg][ddg][e] *= cc;
                }
            // ---- PV: A = P in-regs (k-slot sigma), B = V from LDS ----
#pragma unroll
            for (int m = 0; m < 2; ++m) {
                short8 Ph[2], Pl[2];
#pragma unroll
                for (int rg = 0; rg < 2; ++rg)
#pragma unroll
                    for (int e = 0; e < 4; ++e) {
                        Ph[rg][e]     = pah[rg][2 * m][e];
                        Ph[rg][4 + e] = pah[rg][2 * m + 1][e];
                        Pl[rg][e]     = pal[rg][2 * m][e];
                        Pl[rg][4 + e] = pal[rg][2 * m + 1][e];
                    }
#pragma unroll
                for (int ddg = 0; ddg < 4; ++ddg) {
                    const int dd = ddg * 16 + lr;
                    const int s7 = dd & 7;
                    const int ch0 = (4 * m + (lg >> 1)) ^ s7;
                    const int ch1 = (4 * m + 2 + (lg >> 1)) ^ s7;
                    const int hw = (lg & 1) * 4;
                    s16x4 va0 = *(const s16x4*)&Vlds[0][dd * 64 + ch0 * 8 + hw];
                    s16x4 va1 = *(const s16x4*)&Vlds[0][dd * 64 + ch1 * 8 + hw];
                    s16x4 vb0 = *(const s16x4*)&Vlds[1][dd * 64 + ch0 * 8 + hw];
                    s16x4 vb1 = *(const s16x4*)&Vlds[1][dd * 64 + ch1 * 8 + hw];
                    short8 vh, vl;
#pragma unroll
                    for (int e = 0; e < 4; ++e) {
                        vh[e] = va0[e]; vh[4 + e] = va1[e];
                        vl[e] = vb0[e]; vl[4 + e] = vb1[e];
                    }
#pragma unroll
                    for (int rg = 0; rg < 2; ++rg) {
                        f32x4 a = O[rg][ddg];
                        a = __builtin_amdgcn_mfma_f32_16x16x32_bf16(Ph[rg], vh, a, 0, 0, 0);
                        a = __builtin_amdgcn_mfma_f32_16x16x32_bf16(Ph[rg], vl, a, 0, 0, 0);
                        a = __builtin_amdgcn_mfma_f32_16x16x32_bf16(Pl[rg], vh, a, 0, 0, 0);
                        O[rg][ddg] = a;
                    }
                }
            }
        }
    }
    // ---- epilogue ----
#pragma unroll
    for (int rg = 0; rg < 2; ++rg) {
        float invv = (lsum[rg] > 0.f) ? 1.f / lsum[rg] : 0.f;
#pragma unroll
        for (int e = 0; e < 4; ++e) {
            float ie = __shfl(invv, lg * 4 + e);
            int q = qw + rg * 16 + lg * 4 + e;
            if (q < LDIM) {
#pragma unroll
                for (int ddg = 0; ddg < 4; ++ddg) {
                    float v = O[rg][ddg][e] * ie;
                    short hi, lo; split2(v, hi, lo);
                    size_t o = ((size_t)b * LDIM + q) * CDIM + h * HD + ddg * 16 + lr;
                    Yh[o] = hi; Yl[o] = lo;
                }
            }
        }
    }
}

extern "C" void kernel_launch(void* const* d_in, const int* in_sizes, int n_in,
                              void* d_out, int out_size, void* d_ws, size_t ws_size,
                              hipStream_t stream)
{
    const float* x      = (const float*)d_in[0];
    const float* W_attn = (const float*)d_in[1];
    const float* W_proj = (const float*)d_in[2];
    float* out = (float*)d_out;

    const size_t xN  = (size_t)MROWS * CDIM;
    const size_t waN = (size_t)CDIM * 3 * CDIM;
    const size_t wpN = (size_t)CDIM * CDIM;
    const size_t qkN = (size_t)BATCH * NH * LDIM * HD;
    const size_t vtN = (size_t)BATCH * NH * HD * LPAD;

    char* p = (char*)d_ws;
    short* Xh  = (short*)p; p += xN * 2;    // aliased later as Yh
    short* Xl  = (short*)p; p += xN * 2;    // aliased later as Yl
    short* Wth = (short*)p; p += waN * 2;
    short* Wtl = (short*)p; p += waN * 2;
    short* Pth = (short*)p; p += wpN * 2;
    short* Ptl = (short*)p; p += wpN * 2;
    short* Qh  = (short*)p; p += qkN * 2;
    short* Ql  = (short*)p; p += qkN * 2;
    short* Kh  = (short*)p; p += qkN * 2;
    short* Kl  = (short*)p; p += qkN * 2;
    short* Vth = (short*)p; p += vtN * 2;
    short* Vtl = (short*)p; p += vtN * 2;
    short* Yh = Xh;   // x dead after QKV GEMM
    short* Yl = Xl;

    convsplit_kernel<<<2048, 256, 0, stream>>>(x, Xh, Xl, (int)(xN / 4));
    transconv_kernel<<<dim3(3 * CDIM / 32, CDIM / 32), 256, 0, stream>>>(
        W_attn, Wth, Wtl, CDIM, 3 * CDIM);
    transconv_kernel<<<dim3(CDIM / 32, CDIM / 32), 256, 0, stream>>>(
        W_proj, Pth, Ptl, CDIM, CDIM);

    gemm_mfma_kernel<0><<<dim3(3 * CDIM / 128, (MROWS + 127) / 128), 256, 0, stream>>>(
        Xh, Xl, Wth, Wtl, Qh, Ql, Kh, Kl, Vth, Vtl, nullptr);

    attn_mfma_kernel<<<dim3((LDIM + 127) / 128, BATCH * NH), 256, 0, stream>>>(
        Qh, Ql, Kh, Kl, Vth, Vtl, Yh, Yl);

    gemm_mfma_kernel<1><<<dim3(CDIM / 128, (MROWS + 127) / 128), 256, 0, stream>>>(
        Yh, Yl, Pth, Ptl, nullptr, nullptr, nullptr, nullptr, nullptr, nullptr, out);
}

// Round 9
// 533.920 us; speedup vs baseline: 1.2389x; 1.2389x over previous
//
#include <hip/hip_runtime.h>
#include <hip/hip_bf16.h>

constexpr int BATCH = 4;
constexpr int MEMK  = 128;
constexpr int CDIM  = 768;
constexpr int NH    = 12;
constexpr int HD    = 64;
constexpr int LDIM  = 2177;              // MEMK + 1 + 2048
constexpr int MROWS = BATCH * LDIM;      // 8708
constexpr int LPAD  = 2240;              // Vt row length

typedef __attribute__((ext_vector_type(4))) float f32x4;
typedef __attribute__((ext_vector_type(8))) short short8;
typedef __attribute__((ext_vector_type(4))) short s16x4;

__device__ __forceinline__ short f2bf(float f) {
    unsigned u = __builtin_bit_cast(unsigned, f);
    u = (u + 0x7FFFu + ((u >> 16) & 1u)) >> 16;
    return (short)u;
}
__device__ __forceinline__ float bf2f(short s) {
    unsigned u = ((unsigned)(unsigned short)s) << 16;
    return __builtin_bit_cast(float, u);
}
__device__ __forceinline__ void split2(float v, short& h, short& l) {
    h = f2bf(v);
    l = f2bf(v - bf2f(h));
}
__device__ __forceinline__ void gload16(const void* g, void* l) {
    __builtin_amdgcn_global_load_lds(
        (const __attribute__((address_space(1))) void*)g,
        (__attribute__((address_space(3))) void*)l, 16, 0, 0);
}

// ---------------- convert fp32 -> bf16 hi/lo planes (row-major) ----------------
__global__ __launch_bounds__(256)
void convsplit_kernel(const float* __restrict__ src, short* __restrict__ h,
                      short* __restrict__ l, int n4)
{
    for (int i = blockIdx.x * blockDim.x + threadIdx.x; i < n4;
         i += gridDim.x * blockDim.x) {
        float4 v = ((const float4*)src)[i];
        short hs[4], ls[4];
        split2(v.x, hs[0], ls[0]); split2(v.y, hs[1], ls[1]);
        split2(v.z, hs[2], ls[2]); split2(v.w, hs[3], ls[3]);
        ((short4*)h)[i] = make_short4(hs[0], hs[1], hs[2], hs[3]);
        ((short4*)l)[i] = make_short4(ls[0], ls[1], ls[2], ls[3]);
    }
}

// ---------------- transpose + convert: W[K][N] -> Wt hi/lo [N][K] ----------------
__global__ __launch_bounds__(256)
void transconv_kernel(const float* __restrict__ W, short* __restrict__ th,
                      short* __restrict__ tl, int K, int N)
{
    __shared__ float tile[32][33];
    const int k0 = blockIdx.y * 32, n0 = blockIdx.x * 32;
    const int tx = threadIdx.x & 31, ty = threadIdx.x >> 5;   // 32 x 8
#pragma unroll
    for (int j = 0; j < 4; ++j)
        tile[ty + j * 8][tx] = W[(size_t)(k0 + ty + j * 8) * N + n0 + tx];
    __syncthreads();
#pragma unroll
    for (int j = 0; j < 4; ++j) {
        float v = tile[tx][ty + j * 8];
        short hi, lo; split2(v, hi, lo);
        size_t o = (size_t)(n0 + ty + j * 8) * K + k0 + tx;
        th[o] = hi; tl[o] = lo;
    }
}

// ---------------- MFMA GEMM: A[M][768] (hi/lo) x Bt[N][768] (hi/lo) ----------------
// EPI: 0 = QKV scatter epilogue (Q pre-scaled by 0.125), 1 = plain fp32 out.
template<int EPI>
__global__ __launch_bounds__(256)
void gemm_mfma_kernel(const short* __restrict__ Ah, const short* __restrict__ Al,
                      const short* __restrict__ Bh, const short* __restrict__ Bl,
                      short* __restrict__ Qh, short* __restrict__ Ql,
                      short* __restrict__ Kh, short* __restrict__ Kl,
                      short* __restrict__ Vth, short* __restrict__ Vtl,
                      float* __restrict__ Of)
{
    constexpr int KD = 768;
    __shared__ short lds[4][128 * 32];   // Ah, Al, Bh, Bl tiles (8KB each)
    const int tid  = threadIdx.x;
    const int lane = tid & 63;
    const int w    = tid >> 6;
    const int wr = w >> 1, wc = w & 1;
    const int lr = lane & 15, lg = lane >> 4;
    const int row0 = blockIdx.y * 128, col0 = blockIdx.x * 128;

    f32x4 acc[4][4];
#pragma unroll
    for (int m = 0; m < 4; ++m)
#pragma unroll
        for (int n = 0; n < 4; ++n) acc[m][n] = (f32x4){0.f, 0.f, 0.f, 0.f};

    for (int kt = 0; kt < KD / 32; ++kt) {
        const int k0 = kt * 32;
        __syncthreads();
#pragma unroll
        for (int q = 0; q < 2; ++q) {
            const int c = q * 256 + tid;
            const int r = c >> 2, s = c & 3;
            const int ar = min(row0 + r, MROWS - 1);
            const int br = col0 + r;
            const size_t aoff = (size_t)ar * KD + k0 + s * 8;
            const size_t boff = (size_t)br * KD + k0 + s * 8;
            gload16(Ah + aoff, &lds[0][c * 8]);
            gload16(Al + aoff, &lds[1][c * 8]);
            gload16(Bh + boff, &lds[2][c * 8]);
            gload16(Bl + boff, &lds[3][c * 8]);
        }
        __syncthreads();

        short8 afh[4], afl[4], bfh[4], bfl[4];
#pragma unroll
        for (int m = 0; m < 4; ++m) {
            int r = wr * 64 + m * 16 + lr;
            afh[m] = *(const short8*)&lds[0][r * 32 + lg * 8];
            afl[m] = *(const short8*)&lds[1][r * 32 + lg * 8];
        }
#pragma unroll
        for (int n = 0; n < 4; ++n) {
            int r = wc * 64 + n * 16 + lr;
            bfh[n] = *(const short8*)&lds[2][r * 32 + lg * 8];
            bfl[n] = *(const short8*)&lds[3][r * 32 + lg * 8];
        }
#pragma unroll
        for (int m = 0; m < 4; ++m)
#pragma unroll
            for (int n = 0; n < 4; ++n) {
                f32x4 a = acc[m][n];
                a = __builtin_amdgcn_mfma_f32_16x16x32_bf16(afh[m], bfh[n], a, 0, 0, 0);
                a = __builtin_amdgcn_mfma_f32_16x16x32_bf16(afl[m], bfh[n], a, 0, 0, 0);
                a = __builtin_amdgcn_mfma_f32_16x16x32_bf16(afh[m], bfl[n], a, 0, 0, 0);
                acc[m][n] = a;
            }
    }

#pragma unroll
    for (int n = 0; n < 4; ++n) {
        const int colb = col0 + wc * 64 + n * 16;
        if (EPI == 0) {
            const int sel = colb / CDIM;
            const int c0  = colb - sel * CDIM;
            const int h   = c0 >> 6;
            const int dd  = (c0 & 63) + lr;
            const float scl = (sel == 0) ? 0.125f : 1.0f;   // exact: Q pre-scale
#pragma unroll
            for (int m = 0; m < 4; ++m)
#pragma unroll
                for (int e = 0; e < 4; ++e) {
                    int mg = row0 + wr * 64 + m * 16 + lg * 4 + e;
                    if (mg >= MROWS) continue;
                    int b = mg / LDIM, l = mg - b * LDIM;
                    short hi, lo; split2(acc[m][n][e] * scl, hi, lo);
                    if (sel == 0) {
                        size_t o = (((size_t)(b * NH + h)) * LDIM + l) * HD + dd;
                        Qh[o] = hi; Ql[o] = lo;
                    } else if (sel == 1) {
                        size_t o = (((size_t)(b * NH + h)) * LDIM + l) * HD + dd;
                        Kh[o] = hi; Kl[o] = lo;
                    } else {
                        size_t o = (((size_t)(b * NH + h)) * HD + dd) * LPAD + l;
                        Vth[o] = hi; Vtl[o] = lo;
                    }
                }
        } else {
#pragma unroll
            for (int m = 0; m < 4; ++m)
#pragma unroll
                for (int e = 0; e < 4; ++e) {
                    int mg = row0 + wr * 64 + m * 16 + lg * 4 + e;
                    if (mg >= MROWS) continue;
                    Of[(size_t)mg * CDIM + colb + lr] = acc[m][n][e];
                }
        }
    }
}

// ---------------- MFMA flash attention v3b ----------------
// Same as v3 (P in registers, k-slot remapped PV) but launch_bounds (256,3):
// ~170 VGPR cap fits the ~150-160 live set without spilling -> 3 blocks/CU.
__global__ __launch_bounds__(256, 3)
void attn_mfma_kernel(const short* __restrict__ Qh, const short* __restrict__ Ql,
                      const short* __restrict__ Kh, const short* __restrict__ Kl,
                      const short* __restrict__ Vth, const short* __restrict__ Vtl,
                      short* __restrict__ Yh, short* __restrict__ Yl)
{
    __shared__ short Klds[2][64 * 64];   // [plane][key][d] XOR-swizzled, 16KB
    __shared__ short Vlds[2][64 * 64];   // [plane][d][key] XOR-swizzled, 16KB
    const int tid  = threadIdx.x;
    const int lane = tid & 63;
    const int w    = tid >> 6;
    const int lr = lane & 15, lg = lane >> 4;
    const int bh = blockIdx.y;
    const int b = bh / NH, h = bh % NH;
    constexpr int NXB = (LDIM + 127) / 128;          // 18
    const int qb = (NXB - 1 - (int)blockIdx.x) * 128; // heavy blocks first
    const int qw = qb + w * 32;

    int mynt;
    if (qw >= LDIM) mynt = 0;
    else if (qw <= MEMK && MEMK <= qw + 31) mynt = (LDIM - 1) / 64 + 1;
    else if (qw + 31 < MEMK) mynt = MEMK / 64 + 1;
    else mynt = min(qw + 31, LDIM - 1) / 64 + 1;
    int bnt;
    if (qb <= MEMK && MEMK <= qb + 127) bnt = (LDIM - 1) / 64 + 1;
    else if (qb + 127 < MEMK) bnt = MEMK / 64 + 1;
    else bnt = min(qb + 127, LDIM - 1) / 64 + 1;

    int rkmax[2];
#pragma unroll
    for (int rg = 0; rg < 2; ++rg) {
        int q = qw + rg * 16 + lr;
        rkmax[rg] = (q < MEMK) ? MEMK : (q == MEMK) ? (LDIM - 1)
                  : (q < LDIM) ? q : -1;
    }

    // Q fragments (B-operand), pre-scaled by 0.125 at QKV epilogue
    short8 qfh[2][2], qfl[2][2];
#pragma unroll
    for (int rg = 0; rg < 2; ++rg)
#pragma unroll
        for (int dc = 0; dc < 2; ++dc) {
            int qr = min(qw + rg * 16 + lr, LDIM - 1);
            size_t off = ((size_t)bh * LDIM + qr) * HD + dc * 32 + lg * 8;
            qfh[rg][dc] = *(const short8*)(Qh + off);
            qfl[rg][dc] = *(const short8*)(Ql + off);
        }

    f32x4 O[2][4];
#pragma unroll
    for (int rg = 0; rg < 2; ++rg)
#pragma unroll
        for (int g = 0; g < 4; ++g) O[rg][g] = (f32x4){0.f, 0.f, 0.f, 0.f};
    float mrun[2] = {-INFINITY, -INFINITY};
    float lsum[2] = {0.f, 0.f};

    const short* Khb = Kh  + (size_t)bh * LDIM * HD;
    const short* Klb = Kl  + (size_t)bh * LDIM * HD;
    const short* Vhb = Vth + (size_t)bh * HD * LPAD;
    const short* Vlb = Vtl + (size_t)bh * HD * LPAD;

    for (int t = 0; t < bnt; ++t) {
        const int k0 = t * 64;
        __syncthreads();                 // prev-tile LDS reads complete
#pragma unroll
        for (int it = 0; it < 2; ++it) {
            int c = it * 256 + tid;      // 16B chunk id, lane-stride 16B
            int row = c >> 3, j = c & 7;
            int sw = ((j ^ (row & 7)) << 3);
            int krow = min(k0 + row, LDIM - 1);
            gload16(Khb + (size_t)krow * HD + sw, &Klds[0][c * 8]);
            gload16(Klb + (size_t)krow * HD + sw, &Klds[1][c * 8]);
            gload16(Vhb + (size_t)row * LPAD + k0 + sw, &Vlds[0][c * 8]);
            gload16(Vlb + (size_t)row * LPAD + k0 + sw, &Vlds[1][c * 8]);
        }
        __syncthreads();                 // vmcnt drained by compiler

        if (t < mynt) {
            // ---- QK^T swapped: S[key][q], A=K from LDS, B=Q regs ----
            f32x4 S[2][4];
#pragma unroll
            for (int kg = 0; kg < 4; ++kg) {
                short8 kfh[2], kfl[2];
#pragma unroll
                for (int dc = 0; dc < 2; ++dc) {
                    int key = kg * 16 + lr;
                    int cj = (dc * 4 + lg) ^ (key & 7);
                    kfh[dc] = *(const short8*)&Klds[0][key * 64 + cj * 8];
                    kfl[dc] = *(const short8*)&Klds[1][key * 64 + cj * 8];
                }
#pragma unroll
                for (int rg = 0; rg < 2; ++rg) {
                    f32x4 a = (f32x4){0.f, 0.f, 0.f, 0.f};
#pragma unroll
                    for (int dc = 0; dc < 2; ++dc) {
                        a = __builtin_amdgcn_mfma_f32_16x16x32_bf16(kfh[dc], qfh[rg][dc], a, 0, 0, 0);
                        a = __builtin_amdgcn_mfma_f32_16x16x32_bf16(kfl[dc], qfh[rg][dc], a, 0, 0, 0);
                        a = __builtin_amdgcn_mfma_f32_16x16x32_bf16(kfh[dc], qfl[rg][dc], a, 0, 0, 0);
                    }
                    S[rg][kg] = a;
                }
            }
            // ---- softmax (rows lane-local), P -> registers as bf16 hi/lo ----
            float corr2[2];
            s16x4 pah[2][4], pal[2][4];
#pragma unroll
            for (int rg = 0; rg < 2; ++rg) {
                const int rel = rkmax[rg] - k0 - lg * 4;
                float mx = -INFINITY;
#pragma unroll
                for (int kg = 0; kg < 4; ++kg)
#pragma unroll
                    for (int e = 0; e < 4; ++e) {
                        float v = S[rg][kg][e];
                        v = (kg * 16 + e <= rel) ? v : -INFINITY;
                        S[rg][kg][e] = v;
                        mx = fmaxf(mx, v);
                    }
                mx = fmaxf(mx, __shfl_xor(mx, 16));
                mx = fmaxf(mx, __shfl_xor(mx, 32));
                float nm = fmaxf(mrun[rg], mx);
                float corr = (nm == -INFINITY) ? 1.f : __expf(mrun[rg] - nm);
                mrun[rg] = nm;
                float ps = 0.f;
#pragma unroll
                for (int kg = 0; kg < 4; ++kg)
#pragma unroll
                    for (int e = 0; e < 4; ++e) {
                        float v = S[rg][kg][e];
                        float pp = (v == -INFINITY) ? 0.f : __expf(v - nm);
                        ps += pp;
                        short hh, ll; split2(pp, hh, ll);
                        pah[rg][kg][e] = hh; pal[rg][kg][e] = ll;
                    }
                ps += __shfl_xor(ps, 16);
                ps += __shfl_xor(ps, 32);
                lsum[rg] = lsum[rg] * corr + ps;
                corr2[rg] = corr;
            }
            // ---- rescale O (corr redistributed q=lr -> q=lg*4+e) ----
#pragma unroll
            for (int rg = 0; rg < 2; ++rg)
#pragma unroll
                for (int e = 0; e < 4; ++e) {
                    float cc = __shfl(corr2[rg], lg * 4 + e);
#pragma unroll
                    for (int ddg = 0; ddg < 4; ++ddg) O[rg][ddg][e] *= cc;
                }
            // ---- PV: A = P in-regs (k-slot sigma), B = V from LDS ----
#pragma unroll
            for (int m = 0; m < 2; ++m) {
                short8 Ph[2], Pl[2];
#pragma unroll
                for (int rg = 0; rg < 2; ++rg)
#pragma unroll
                    for (int e = 0; e < 4; ++e) {
                        Ph[rg][e]     = pah[rg][2 * m][e];
                        Ph[rg][4 + e] = pah[rg][2 * m + 1][e];
                        Pl[rg][e]     = pal[rg][2 * m][e];
                        Pl[rg][4 + e] = pal[rg][2 * m + 1][e];
                    }
#pragma unroll
                for (int ddg = 0; ddg < 4; ++ddg) {
                    const int dd = ddg * 16 + lr;
                    const int s7 = dd & 7;
                    const int ch0 = (4 * m + (lg >> 1)) ^ s7;
                    const int ch1 = (4 * m + 2 + (lg >> 1)) ^ s7;
                    const int hw = (lg & 1) * 4;
                    s16x4 va0 = *(const s16x4*)&Vlds[0][dd * 64 + ch0 * 8 + hw];
                    s16x4 va1 = *(const s16x4*)&Vlds[0][dd * 64 + ch1 * 8 + hw];
                    s16x4 vb0 = *(const s16x4*)&Vlds[1][dd * 64 + ch0 * 8 + hw];
                    s16x4 vb1 = *(const s16x4*)&Vlds[1][dd * 64 + ch1 * 8 + hw];
                    short8 vh, vl;
#pragma unroll
                    for (int e = 0; e < 4; ++e) {
                        vh[e] = va0[e]; vh[4 + e] = va1[e];
                        vl[e] = vb0[e]; vl[4 + e] = vb1[e];
                    }
#pragma unroll
                    for (int rg = 0; rg < 2; ++rg) {
                        f32x4 a = O[rg][ddg];
                        a = __builtin_amdgcn_mfma_f32_16x16x32_bf16(Ph[rg], vh, a, 0, 0, 0);
                        a = __builtin_amdgcn_mfma_f32_16x16x32_bf16(Ph[rg], vl, a, 0, 0, 0);
                        a = __builtin_amdgcn_mfma_f32_16x16x32_bf16(Pl[rg], vh, a, 0, 0, 0);
                        O[rg][ddg] = a;
                    }
                }
            }
        }
    }
    // ---- epilogue ----
#pragma unroll
    for (int rg = 0; rg < 2; ++rg) {
        float invv = (lsum[rg] > 0.f) ? 1.f / lsum[rg] : 0.f;
#pragma unroll
        for (int e = 0; e < 4; ++e) {
            float ie = __shfl(invv, lg * 4 + e);
            int q = qw + rg * 16 + lg * 4 + e;
            if (q < LDIM) {
#pragma unroll
                for (int ddg = 0; ddg < 4; ++ddg) {
                    float v = O[rg][ddg][e] * ie;
                    short hi, lo; split2(v, hi, lo);
                    size_t o = ((size_t)b * LDIM + q) * CDIM + h * HD + ddg * 16 + lr;
                    Yh[o] = hi; Yl[o] = lo;
                }
            }
        }
    }
}

extern "C" void kernel_launch(void* const* d_in, const int* in_sizes, int n_in,
                              void* d_out, int out_size, void* d_ws, size_t ws_size,
                              hipStream_t stream)
{
    const float* x      = (const float*)d_in[0];
    const float* W_attn = (const float*)d_in[1];
    const float* W_proj = (const float*)d_in[2];
    float* out = (float*)d_out;

    const size_t xN  = (size_t)MROWS * CDIM;
    const size_t waN = (size_t)CDIM * 3 * CDIM;
    const size_t wpN = (size_t)CDIM * CDIM;
    const size_t qkN = (size_t)BATCH * NH * LDIM * HD;
    const size_t vtN = (size_t)BATCH * NH * HD * LPAD;

    char* p = (char*)d_ws;
    short* Xh  = (short*)p; p += xN * 2;    // aliased later as Yh
    short* Xl  = (short*)p; p += xN * 2;    // aliased later as Yl
    short* Wth = (short*)p; p += waN * 2;
    short* Wtl = (short*)p; p += waN * 2;
    short* Pth = (short*)p; p += wpN * 2;
    short* Ptl = (short*)p; p += wpN * 2;
    short* Qh  = (short*)p; p += qkN * 2;
    short* Ql  = (short*)p; p += qkN * 2;
    short* Kh  = (short*)p; p += qkN * 2;
    short* Kl  = (short*)p; p += qkN * 2;
    short* Vth = (short*)p; p += vtN * 2;
    short* Vtl = (short*)p; p += vtN * 2;
    short* Yh = Xh;   // x dead after QKV GEMM
    short* Yl = Xl;

    convsplit_kernel<<<2048, 256, 0, stream>>>(x, Xh, Xl, (int)(xN / 4));
    transconv_kernel<<<dim3(3 * CDIM / 32, CDIM / 32), 256, 0, stream>>>(
        W_attn, Wth, Wtl, CDIM, 3 * CDIM);
    transconv_kernel<<<dim3(CDIM / 32, CDIM / 32), 256, 0, stream>>>(
        W_proj, Pth, Ptl, CDIM, CDIM);

    gemm_mfma_kernel<0><<<dim3(3 * CDIM / 128, (MROWS + 127) / 128), 256, 0, stream>>>(
        Xh, Xl, Wth, Wtl, Qh, Ql, Kh, Kl, Vth, Vtl, nullptr);

    attn_mfma_kernel<<<dim3((LDIM + 127) / 128, BATCH * NH), 256, 0, stream>>>(
        Qh, Ql, Kh, Kl, Vth, Vtl, Yh, Yl);

    gemm_mfma_kernel<1><<<dim3(CDIM / 128, (MROWS + 127) / 128), 256, 0, stream>>>(
        Yh, Yl, Pth, Ptl, nullptr, nullptr, nullptr, nullptr, nullptr, nullptr, out);
}

// Round 16
// 519.739 us; speedup vs baseline: 1.2727x; 1.0273x over previous
//
#include <hip/hip_runtime.h>
#include <hip/hip_bf16.h>

constexpr int BATCH = 4;
constexpr int MEMK  = 128;
constexpr int CDIM  = 768;
constexpr int NH    = 12;
constexpr int HD    = 64;
constexpr int LDIM  = 2177;              // MEMK + 1 + 2048
constexpr int MROWS = BATCH * LDIM;      // 8708
constexpr int LPAD  = 2240;              // Vt row length

typedef __attribute__((ext_vector_type(4))) float f32x4;
typedef __attribute__((ext_vector_type(8))) short short8;
typedef __attribute__((ext_vector_type(4))) short s16x4;
typedef __attribute__((ext_vector_type(4))) unsigned int u32x4;

__device__ __forceinline__ short f2bf(float f) {
    unsigned u = __builtin_bit_cast(unsigned, f);
    u = (u + 0x7FFFu + ((u >> 16) & 1u)) >> 16;
    return (short)u;
}
__device__ __forceinline__ float bf2f(short s) {
    unsigned u = ((unsigned)(unsigned short)s) << 16;
    return __builtin_bit_cast(float, u);
}
__device__ __forceinline__ void split2(float v, short& h, short& l) {
    h = f2bf(v);
    l = f2bf(v - bf2f(h));
}
// packed: 2 f32 -> 1 uint of 2 bf16 (RNE); memcpy instead of bit_cast
// (R13 lesson: __hip_bfloat162 is not trivially copyable on ROCm headers)
__device__ __forceinline__ unsigned pkbf(float a, float b) {
    __hip_bfloat162 t = __float22bfloat162_rn(make_float2(a, b));
    unsigned r;
    __builtin_memcpy(&r, &t, 4);
    return r;
}
__device__ __forceinline__ void gload16(const void* g, void* l) {
    __builtin_amdgcn_global_load_lds(
        (const __attribute__((address_space(1))) void*)g,
        (__attribute__((address_space(3))) void*)l, 16, 0, 0);
}

// ---------------- convert fp32 -> bf16 hi/lo planes (row-major) ----------------
__global__ __launch_bounds__(256)
void convsplit_kernel(const float* __restrict__ src, short* __restrict__ h,
                      short* __restrict__ l, int n4)
{
    for (int i = blockIdx.x * blockDim.x + threadIdx.x; i < n4;
         i += gridDim.x * blockDim.x) {
        float4 v = ((const float4*)src)[i];
        short hs[4], ls[4];
        split2(v.x, hs[0], ls[0]); split2(v.y, hs[1], ls[1]);
        split2(v.z, hs[2], ls[2]); split2(v.w, hs[3], ls[3]);
        ((short4*)h)[i] = make_short4(hs[0], hs[1], hs[2], hs[3]);
        ((short4*)l)[i] = make_short4(ls[0], ls[1], ls[2], ls[3]);
    }
}

// ---------------- transpose + convert: W[K][N] -> Wt hi/lo [N][K] ----------------
__global__ __launch_bounds__(256)
void transconv_kernel(const float* __restrict__ W, short* __restrict__ th,
                      short* __restrict__ tl, int K, int N)
{
    __shared__ float tile[32][33];
    const int k0 = blockIdx.y * 32, n0 = blockIdx.x * 32;
    const int tx = threadIdx.x & 31, ty = threadIdx.x >> 5;   // 32 x 8
#pragma unroll
    for (int j = 0; j < 4; ++j)
        tile[ty + j * 8][tx] = W[(size_t)(k0 + ty + j * 8) * N + n0 + tx];
    __syncthreads();
#pragma unroll
    for (int j = 0; j < 4; ++j) {
        float v = tile[tx][ty + j * 8];
        short hi, lo; split2(v, hi, lo);
        size_t o = (size_t)(n0 + ty + j * 8) * K + k0 + tx;
        th[o] = hi; tl[o] = lo;
    }
}

// ---------------- MFMA GEMM: A[M][768] (hi/lo) x Bt[N][768] (hi/lo) ----------------
// EPI: 0 = QKV scatter epilogue (Q pre-scaled by 0.125), 1 = plain fp32 out.
template<int EPI>
__global__ __launch_bounds__(256)
void gemm_mfma_kernel(const short* __restrict__ Ah, const short* __restrict__ Al,
                      const short* __restrict__ Bh, const short* __restrict__ Bl,
                      short* __restrict__ Qh, short* __restrict__ Ql,
                      short* __restrict__ Kh, short* __restrict__ Kl,
                      short* __restrict__ Vth, short* __restrict__ Vtl,
                      float* __restrict__ Of)
{
    constexpr int KD = 768;
    __shared__ short lds[4][128 * 32];   // Ah, Al, Bh, Bl tiles (8KB each)
    const int tid  = threadIdx.x;
    const int lane = tid & 63;
    const int w    = tid >> 6;
    const int wr = w >> 1, wc = w & 1;
    const int lr = lane & 15, lg = lane >> 4;
    const int row0 = blockIdx.y * 128, col0 = blockIdx.x * 128;

    f32x4 acc[4][4];
#pragma unroll
    for (int m = 0; m < 4; ++m)
#pragma unroll
        for (int n = 0; n < 4; ++n) acc[m][n] = (f32x4){0.f, 0.f, 0.f, 0.f};

    for (int kt = 0; kt < KD / 32; ++kt) {
        const int k0 = kt * 32;
        __syncthreads();
#pragma unroll
        for (int q = 0; q < 2; ++q) {
            const int c = q * 256 + tid;
            const int r = c >> 2, s = c & 3;
            const int ar = min(row0 + r, MROWS - 1);
            const int br = col0 + r;
            const size_t aoff = (size_t)ar * KD + k0 + s * 8;
            const size_t boff = (size_t)br * KD + k0 + s * 8;
            gload16(Ah + aoff, &lds[0][c * 8]);
            gload16(Al + aoff, &lds[1][c * 8]);
            gload16(Bh + boff, &lds[2][c * 8]);
            gload16(Bl + boff, &lds[3][c * 8]);
        }
        __syncthreads();

        short8 afh[4], afl[4], bfh[4], bfl[4];
#pragma unroll
        for (int m = 0; m < 4; ++m) {
            int r = wr * 64 + m * 16 + lr;
            afh[m] = *(const short8*)&lds[0][r * 32 + lg * 8];
            afl[m] = *(const short8*)&lds[1][r * 32 + lg * 8];
        }
#pragma unroll
        for (int n = 0; n < 4; ++n) {
            int r = wc * 64 + n * 16 + lr;
            bfh[n] = *(const short8*)&lds[2][r * 32 + lg * 8];
            bfl[n] = *(const short8*)&lds[3][r * 32 + lg * 8];
        }
#pragma unroll
        for (int m = 0; m < 4; ++m)
#pragma unroll
            for (int n = 0; n < 4; ++n) {
                f32x4 a = acc[m][n];
                a = __builtin_amdgcn_mfma_f32_16x16x32_bf16(afh[m], bfh[n], a, 0, 0, 0);
                a = __builtin_amdgcn_mfma_f32_16x16x32_bf16(afl[m], bfh[n], a, 0, 0, 0);
                a = __builtin_amdgcn_mfma_f32_16x16x32_bf16(afh[m], bfl[n], a, 0, 0, 0);
                acc[m][n] = a;
            }
    }

#pragma unroll
    for (int n = 0; n < 4; ++n) {
        const int colb = col0 + wc * 64 + n * 16;
        if (EPI == 0) {
            const int sel = colb / CDIM;
            const int c0  = colb - sel * CDIM;
            const int h   = c0 >> 6;
            const int dd  = (c0 & 63) + lr;
            const float scl = (sel == 0) ? 0.125f : 1.0f;   // exact: Q pre-scale
#pragma unroll
            for (int m = 0; m < 4; ++m)
#pragma unroll
                for (int e = 0; e < 4; ++e) {
                    int mg = row0 + wr * 64 + m * 16 + lg * 4 + e;
                    if (mg >= MROWS) continue;
                    int b = mg / LDIM, l = mg - b * LDIM;
                    short hi, lo; split2(acc[m][n][e] * scl, hi, lo);
                    if (sel == 0) {
                        size_t o = (((size_t)(b * NH + h)) * LDIM + l) * HD + dd;
                        Qh[o] = hi; Ql[o] = lo;
                    } else if (sel == 1) {
                        size_t o = (((size_t)(b * NH + h)) * LDIM + l) * HD + dd;
                        Kh[o] = hi; Kl[o] = lo;
                    } else {
                        size_t o = (((size_t)(b * NH + h)) * HD + dd) * LPAD + l;
                        Vth[o] = hi; Vtl[o] = lo;
                    }
                }
        } else {
#pragma unroll
            for (int m = 0; m < 4; ++m)
#pragma unroll
                for (int e = 0; e < 4; ++e) {
                    int mg = row0 + wr * 64 + m * 16 + lg * 4 + e;
                    if (mg >= MROWS) continue;
                    Of[(size_t)mg * CDIM + colb + lr] = acc[m][n][e];
                }
        }
    }
}

// ---------------- MFMA flash attention v4 ----------------
// v3 structure (P in registers, k-slot sigma PV) with:
//  - no min-waves bound (R8/R9 lesson: forcing it makes the allocator spill)
//  - packed bf16 P conversion via __float22bfloat162_rn
__global__ __launch_bounds__(256)
void attn_mfma_kernel(const short* __restrict__ Qh, const short* __restrict__ Ql,
                      const short* __restrict__ Kh, const short* __restrict__ Kl,
                      const short* __restrict__ Vth, const short* __restrict__ Vtl,
                      short* __restrict__ Yh, short* __restrict__ Yl)
{
    __shared__ short Klds[2][64 * 64];   // [plane][key][d] XOR-swizzled, 16KB
    __shared__ short Vlds[2][64 * 64];   // [plane][d][key] XOR-swizzled, 16KB
    const int tid  = threadIdx.x;
    const int lane = tid & 63;
    const int w    = tid >> 6;
    const int lr = lane & 15, lg = lane >> 4;
    const int bh = blockIdx.y;
    const int b = bh / NH, h = bh % NH;
    constexpr int NXB = (LDIM + 127) / 128;          // 18
    const int qb = (NXB - 1 - (int)blockIdx.x) * 128; // heavy blocks first
    const int qw = qb + w * 32;

    int mynt;
    if (qw >= LDIM) mynt = 0;
    else if (qw <= MEMK && MEMK <= qw + 31) mynt = (LDIM - 1) / 64 + 1;
    else if (qw + 31 < MEMK) mynt = MEMK / 64 + 1;
    else mynt = min(qw + 31, LDIM - 1) / 64 + 1;
    int bnt;
    if (qb <= MEMK && MEMK <= qb + 127) bnt = (LDIM - 1) / 64 + 1;
    else if (qb + 127 < MEMK) bnt = MEMK / 64 + 1;
    else bnt = min(qb + 127, LDIM - 1) / 64 + 1;

    int rkmax[2];
#pragma unroll
    for (int rg = 0; rg < 2; ++rg) {
        int q = qw + rg * 16 + lr;
        rkmax[rg] = (q < MEMK) ? MEMK : (q == MEMK) ? (LDIM - 1)
                  : (q < LDIM) ? q : -1;
    }

    // Q fragments (B-operand), pre-scaled by 0.125 at QKV epilogue
    short8 qfh[2][2], qfl[2][2];
#pragma unroll
    for (int rg = 0; rg < 2; ++rg)
#pragma unroll
        for (int dc = 0; dc < 2; ++dc) {
            int qr = min(qw + rg * 16 + lr, LDIM - 1);
            size_t off = ((size_t)bh * LDIM + qr) * HD + dc * 32 + lg * 8;
            qfh[rg][dc] = *(const short8*)(Qh + off);
            qfl[rg][dc] = *(const short8*)(Ql + off);
        }

    f32x4 O[2][4];
#pragma unroll
    for (int rg = 0; rg < 2; ++rg)
#pragma unroll
        for (int g = 0; g < 4; ++g) O[rg][g] = (f32x4){0.f, 0.f, 0.f, 0.f};
    float mrun[2] = {-INFINITY, -INFINITY};
    float lsum[2] = {0.f, 0.f};

    const short* Khb = Kh  + (size_t)bh * LDIM * HD;
    const short* Klb = Kl  + (size_t)bh * LDIM * HD;
    const short* Vhb = Vth + (size_t)bh * HD * LPAD;
    const short* Vlb = Vtl + (size_t)bh * HD * LPAD;

    for (int t = 0; t < bnt; ++t) {
        const int k0 = t * 64;
        __syncthreads();                 // prev-tile LDS reads complete
#pragma unroll
        for (int it = 0; it < 2; ++it) {
            int c = it * 256 + tid;      // 16B chunk id, lane-stride 16B
            int row = c >> 3, j = c & 7;
            int sw = ((j ^ (row & 7)) << 3);
            int krow = min(k0 + row, LDIM - 1);
            gload16(Khb + (size_t)krow * HD + sw, &Klds[0][c * 8]);
            gload16(Klb + (size_t)krow * HD + sw, &Klds[1][c * 8]);
            gload16(Vhb + (size_t)row * LPAD + k0 + sw, &Vlds[0][c * 8]);
            gload16(Vlb + (size_t)row * LPAD + k0 + sw, &Vlds[1][c * 8]);
        }
        __syncthreads();                 // vmcnt drained by compiler

        if (t < mynt) {
            // ---- QK^T swapped: S[key][q], A=K from LDS, B=Q regs ----
            f32x4 S[2][4];
#pragma unroll
            for (int kg = 0; kg < 4; ++kg) {
                short8 kfh[2], kfl[2];
#pragma unroll
                for (int dc = 0; dc < 2; ++dc) {
                    int key = kg * 16 + lr;
                    int cj = (dc * 4 + lg) ^ (key & 7);
                    kfh[dc] = *(const short8*)&Klds[0][key * 64 + cj * 8];
                    kfl[dc] = *(const short8*)&Klds[1][key * 64 + cj * 8];
                }
#pragma unroll
                for (int rg = 0; rg < 2; ++rg) {
                    f32x4 a = (f32x4){0.f, 0.f, 0.f, 0.f};
#pragma unroll
                    for (int dc = 0; dc < 2; ++dc) {
                        a = __builtin_amdgcn_mfma_f32_16x16x32_bf16(kfh[dc], qfh[rg][dc], a, 0, 0, 0);
                        a = __builtin_amdgcn_mfma_f32_16x16x32_bf16(kfl[dc], qfh[rg][dc], a, 0, 0, 0);
                        a = __builtin_amdgcn_mfma_f32_16x16x32_bf16(kfh[dc], qfl[rg][dc], a, 0, 0, 0);
                    }
                    S[rg][kg] = a;
                }
            }
            // ---- softmax (rows lane-local); P -> packed bf16 hi/lo uints ----
            float corr2[2];
            unsigned puh[2][4][2], pul[2][4][2];
#pragma unroll
            for (int rg = 0; rg < 2; ++rg) {
                const int rel = rkmax[rg] - k0 - lg * 4;
                float mx = -INFINITY;
#pragma unroll
                for (int kg = 0; kg < 4; ++kg)
#pragma unroll
                    for (int e = 0; e < 4; ++e) {
                        float v = S[rg][kg][e];
                        v = (kg * 16 + e <= rel) ? v : -INFINITY;
                        S[rg][kg][e] = v;
                        mx = fmaxf(mx, v);
                    }
                mx = fmaxf(mx, __shfl_xor(mx, 16));
                mx = fmaxf(mx, __shfl_xor(mx, 32));
                float nm = fmaxf(mrun[rg], mx);
                float corr = (nm == -INFINITY) ? 1.f : __expf(mrun[rg] - nm);
                mrun[rg] = nm;
                float ps = 0.f;
#pragma unroll
                for (int kg = 0; kg < 4; ++kg) {
                    float pv[4];
#pragma unroll
                    for (int e = 0; e < 4; ++e) {
                        float v = S[rg][kg][e];
                        float pp = (v == -INFINITY) ? 0.f : __expf(v - nm);
                        ps += pp;
                        pv[e] = pp;
                    }
                    unsigned h0 = pkbf(pv[0], pv[1]);
                    unsigned h1 = pkbf(pv[2], pv[3]);
                    float l0 = pv[0] - __builtin_bit_cast(float, h0 << 16);
                    float l1 = pv[1] - __builtin_bit_cast(float, h0 & 0xFFFF0000u);
                    float l2 = pv[2] - __builtin_bit_cast(float, h1 << 16);
                    float l3 = pv[3] - __builtin_bit_cast(float, h1 & 0xFFFF0000u);
                    puh[rg][kg][0] = h0; puh[rg][kg][1] = h1;
                    pul[rg][kg][0] = pkbf(l0, l1);
                    pul[rg][kg][1] = pkbf(l2, l3);
                }
                ps += __shfl_xor(ps, 16);
                ps += __shfl_xor(ps, 32);
                lsum[rg] = lsum[rg] * corr + ps;
                corr2[rg] = corr;
            }
            // ---- rescale O (corr redistributed q=lr -> q=lg*4+e) ----
#pragma unroll
            for (int rg = 0; rg < 2; ++rg)
#pragma unroll
                for (int e = 0; e < 4; ++e) {
                    float cc = __shfl(corr2[rg], lg * 4 + e);
#pragma unroll
                    for (int ddg = 0; ddg < 4; ++ddg) O[rg][ddg][e] *= cc;
                }
            // ---- PV: A = P in-regs (k-slot sigma), B = V from LDS ----
#pragma unroll
            for (int m = 0; m < 2; ++m) {
                short8 Ph[2], Pl[2];
#pragma unroll
                for (int rg = 0; rg < 2; ++rg) {
                    u32x4 uh = {puh[rg][2 * m][0], puh[rg][2 * m][1],
                                puh[rg][2 * m + 1][0], puh[rg][2 * m + 1][1]};
                    u32x4 ul = {pul[rg][2 * m][0], pul[rg][2 * m][1],
                                pul[rg][2 * m + 1][0], pul[rg][2 * m + 1][1]};
                    Ph[rg] = __builtin_bit_cast(short8, uh);
                    Pl[rg] = __builtin_bit_cast(short8, ul);
                }
#pragma unroll
                for (int ddg = 0; ddg < 4; ++ddg) {
                    const int dd = ddg * 16 + lr;
                    const int s7 = dd & 7;
                    const int ch0 = (4 * m + (lg >> 1)) ^ s7;
                    const int ch1 = (4 * m + 2 + (lg >> 1)) ^ s7;
                    const int hw = (lg & 1) * 4;
                    s16x4 va0 = *(const s16x4*)&Vlds[0][dd * 64 + ch0 * 8 + hw];
                    s16x4 va1 = *(const s16x4*)&Vlds[0][dd * 64 + ch1 * 8 + hw];
                    s16x4 vb0 = *(const s16x4*)&Vlds[1][dd * 64 + ch0 * 8 + hw];
                    s16x4 vb1 = *(const s16x4*)&Vlds[1][dd * 64 + ch1 * 8 + hw];
                    short8 vh, vl;
#pragma unroll
                    for (int e = 0; e < 4; ++e) {
                        vh[e] = va0[e]; vh[4 + e] = va1[e];
                        vl[e] = vb0[e]; vl[4 + e] = vb1[e];
                    }
#pragma unroll
                    for (int rg = 0; rg < 2; ++rg) {
                        f32x4 a = O[rg][ddg];
                        a = __builtin_amdgcn_mfma_f32_16x16x32_bf16(Ph[rg], vh, a, 0, 0, 0);
                        a = __builtin_amdgcn_mfma_f32_16x16x32_bf16(Ph[rg], vl, a, 0, 0, 0);
                        a = __builtin_amdgcn_mfma_f32_16x16x32_bf16(Pl[rg], vh, a, 0, 0, 0);
                        O[rg][ddg] = a;
                    }
                }
            }
        }
    }
    // ---- epilogue ----
#pragma unroll
    for (int rg = 0; rg < 2; ++rg) {
        float invv = (lsum[rg] > 0.f) ? 1.f / lsum[rg] : 0.f;
#pragma unroll
        for (int e = 0; e < 4; ++e) {
            float ie = __shfl(invv, lg * 4 + e);
            int q = qw + rg * 16 + lg * 4 + e;
            if (q < LDIM) {
#pragma unroll
                for (int ddg = 0; ddg < 4; ++ddg) {
                    float v = O[rg][ddg][e] * ie;
                    short hi, lo; split2(v, hi, lo);
                    size_t o = ((size_t)b * LDIM + q) * CDIM + h * HD + ddg * 16 + lr;
                    Yh[o] = hi; Yl[o] = lo;
                }
            }
        }
    }
}

extern "C" void kernel_launch(void* const* d_in, const int* in_sizes, int n_in,
                              void* d_out, int out_size, void* d_ws, size_t ws_size,
                              hipStream_t stream)
{
    const float* x      = (const float*)d_in[0];
    const float* W_attn = (const float*)d_in[1];
    const float* W_proj = (const float*)d_in[2];
    float* out = (float*)d_out;

    const size_t xN  = (size_t)MROWS * CDIM;
    const size_t waN = (size_t)CDIM * 3 * CDIM;
    const size_t wpN = (size_t)CDIM * CDIM;
    const size_t qkN = (size_t)BATCH * NH * LDIM * HD;
    const size_t vtN = (size_t)BATCH * NH * HD * LPAD;

    char* p = (char*)d_ws;
    short* Xh  = (short*)p; p += xN * 2;    // aliased later as Yh
    short* Xl  = (short*)p; p += xN * 2;    // aliased later as Yl
    short* Wth = (short*)p; p += waN * 2;
    short* Wtl = (short*)p; p += waN * 2;
    short* Pth = (short*)p; p += wpN * 2;
    short* Ptl = (short*)p; p += wpN * 2;
    short* Qh  = (short*)p; p += qkN * 2;
    short* Ql  = (short*)p; p += qkN * 2;
    short* Kh  = (short*)p; p += qkN * 2;
    short* Kl  = (short*)p; p += qkN * 2;
    short* Vth = (short*)p; p += vtN * 2;
    short* Vtl = (short*)p; p += vtN * 2;
    short* Yh = Xh;   // x dead after QKV GEMM
    short* Yl = Xl;

    convsplit_kernel<<<2048, 256, 0, stream>>>(x, Xh, Xl, (int)(xN / 4));
    transconv_kernel<<<dim3(3 * CDIM / 32, CDIM / 32), 256, 0, stream>>>(
        W_attn, Wth, Wtl, CDIM, 3 * CDIM);
    transconv_kernel<<<dim3(CDIM / 32, CDIM / 32), 256, 0, stream>>>(
        W_proj, Pth, Ptl, CDIM, CDIM);

    gemm_mfma_kernel<0><<<dim3(3 * CDIM / 128, (MROWS + 127) / 128), 256, 0, stream>>>(
        Xh, Xl, Wth, Wtl, Qh, Ql, Kh, Kl, Vth, Vtl, nullptr);

    attn_mfma_kernel<<<dim3((LDIM + 127) / 128, BATCH * NH), 256, 0, stream>>>(
        Qh, Ql, Kh, Kl, Vth, Vtl, Yh, Yl);

    gemm_mfma_kernel<1><<<dim3(CDIM / 128, (MROWS + 127) / 128), 256, 0, stream>>>(
        Yh, Yl, Pth, Ptl, nullptr, nullptr, nullptr, nullptr, nullptr, nullptr, out);
}